// Round 3
// baseline (426.749 us; speedup 1.0000x reference)
//
#include <hip/hip_runtime.h>
#include <cstdint>

// ---------------- problem constants ----------------
#define DD     256
#define HH     1024
#define NNSEQ  4096
#define KDIM   3840          // 15 * 256 (conv-as-GEMM K)
#define NSTEPS 120           // KDIM / 32
#define MT     64            // tokens per block (both GEMM kernels)
#define XROWS  78            // MT + 14 halo rows
#define XPITCH 264           // 256 + 8 pad (bf16 elems)
#define APITCH 136           // 128 + 8 pad
#define EPSLN  1e-5f

typedef unsigned short u16;
typedef __attribute__((ext_vector_type(8))) short short8;
typedef __attribute__((ext_vector_type(4))) float f32x4;

#define MFMA(a, b, c) __builtin_amdgcn_mfma_f32_16x16x32_bf16(a, b, c, 0, 0, 0)

__device__ __forceinline__ u16 f2bf(float f) {           // RNE fp32 -> bf16
  unsigned u = __float_as_uint(f);
  u += 0x7FFF + ((u >> 16) & 1);
  return (u16)(u >> 16);
}
__device__ __forceinline__ float bf2f(u16 s) { return __uint_as_float(((unsigned)s) << 16); }

// ------------- pre-pass: all 3 weight transposes (fp32 [R][C] -> bf16 [C][R]) ----
__global__ __launch_bounds__(256) void k_prep(
    const float* __restrict__ wmix, const float* __restrict__ wff1,
    const float* __restrict__ wff2, u16* __restrict__ wmt,
    u16* __restrict__ w1t, u16* __restrict__ w2t)
{
  __shared__ float t[32][33];
  const int b = blockIdx.x;
  const float* src; u16* dst; int R, C, bx, by;
  if (b < 960)       { src = wmix; dst = wmt; R = KDIM; C = DD; bx = b & 7;  by = b >> 3; }
  else if (b < 1216) { const int u = b - 960;  src = wff1; dst = w1t; R = DD; C = HH; bx = u & 31; by = u >> 5; }
  else               { const int u = b - 1216; src = wff2; dst = w2t; R = HH; C = DD; bx = u & 7;  by = u >> 3; }
  const int tc = bx * 32, tr = by * 32;
  const int c = threadIdx.x & 31, r0 = threadIdx.x >> 5;
#pragma unroll
  for (int i = 0; i < 4; ++i) {
    const int r = r0 + i * 8;
    t[r][c] = src[(size_t)(tr + r) * C + tc + c];
  }
  __syncthreads();
#pragma unroll
  for (int i = 0; i < 4; ++i) {
    const int r = r0 + i * 8;
    dst[(size_t)(tc + r) * R + tr + c] = f2bf(t[c][r]);
  }
}

// ---------------- kernel 1: causal conv (MFMA) + residual + LN1 -> h (bf16) ----
// 1024 threads = 16 waves = 4 m-groups x 4 n-groups. Per wave: 16 rows x 64 cols.
__global__ __launch_bounds__(1024) void k_mix_ln1(
    const float* __restrict__ x, const u16* __restrict__ wmt,
    const float* __restrict__ bmix, const float* __restrict__ g1,
    const float* __restrict__ b1, u16* __restrict__ h)
{
  __shared__ u16 xs[XROWS * XPITCH];                 // 41.2 KB
  __shared__ float redS[4][64], redS2[4][64];
  __shared__ float muL[64], invL[64];

  const int tid = threadIdx.x;
  const int wv = tid >> 6, l = tid & 63, q = l >> 4, cl = l & 15;
  const int mg = wv >> 2, ng = wv & 3;
  const long tok0 = (long)blockIdx.x * MT;
  const int n0 = (int)(tok0 & (NNSEQ - 1));          // position within batch (64 | 4096)

  // ---- stage x rows [tok0-14, tok0+63] as bf16 into LDS ----
  {
    const int cslot = (tid & 63) * 4;                // 4 floats/thread, 64 slots/row
    for (int r = tid >> 6; r < XROWS; r += 16) {
      const int nloc = n0 - 14 + r;                  // causal zero-pad within batch
      float4 v = make_float4(0.f, 0.f, 0.f, 0.f);
      if (nloc >= 0) v = *(const float4*)&x[(tok0 - 14 + r) * DD + cslot];
      uint2 pk;
      pk.x = (unsigned)f2bf(v.x) | ((unsigned)f2bf(v.y) << 16);
      pk.y = (unsigned)f2bf(v.z) | ((unsigned)f2bf(v.w) << 16);
      *(uint2*)&xs[r * XPITCH + cslot] = pk;
    }
  }
  __syncthreads();

  // ---- accumulators: this wave's 16 rows x 4 n-tiles ----
  f32x4 acc[4];
#pragma unroll
  for (int nt = 0; nt < 4; ++nt) {
    const float bm = bmix[ng * 64 + nt * 16 + cl];
    acc[nt] = (f32x4){bm, bm, bm, bm};
  }

  const int arow = mg * 16 + cl;                     // A-row (m) for this lane

  // ---- K loop, double-buffered fragment prefetch ----
  short8 af[2]; short8 bfr[2][4];
  af[0] = *(const short8*)&xs[arow * XPITCH + q * 8];
#pragma unroll
  for (int nt = 0; nt < 4; ++nt)
    bfr[0][nt] = *(const short8*)&wmt[(size_t)(ng * 64 + nt * 16 + cl) * KDIM + q * 8];

#pragma unroll 2
  for (int s = 0; s < NSTEPS; ++s) {
    const int cur = s & 1, nxt = cur ^ 1;
    if (s + 1 < NSTEPS) {
      const int s1 = s + 1;
      const int xrow = s1 >> 3, c0 = (s1 & 7) * 32;
      af[nxt] = *(const short8*)&xs[(xrow + arow) * XPITCH + c0 + q * 8];
      const size_t ko = (size_t)(s1 * 32 + q * 8);
#pragma unroll
      for (int nt = 0; nt < 4; ++nt)
        bfr[nxt][nt] = *(const short8*)&wmt[(size_t)(ng * 64 + nt * 16 + cl) * KDIM + ko];
    }
#pragma unroll
    for (int nt = 0; nt < 4; ++nt)
      acc[nt] = MFMA(af[cur], bfr[cur][nt], acc[nt]);
  }

  // ---- residual (fp32 x) ----
#pragma unroll
  for (int nt = 0; nt < 4; ++nt) {
    const int col = ng * 64 + nt * 16 + cl;
#pragma unroll
    for (int reg = 0; reg < 4; ++reg) {
      const int row = mg * 16 + q * 4 + reg;
      acc[nt][reg] += x[(tok0 + row) * DD + col];
    }
  }

  // ---- LN1 row sums: 16-lane shuffle within q-group, then cross-ng via LDS ----
  float ps[4], ps2[4];
#pragma unroll
  for (int reg = 0; reg < 4; ++reg) {
    float s = 0.f, s2 = 0.f;
#pragma unroll
    for (int nt = 0; nt < 4; ++nt) { const float y = acc[nt][reg]; s += y; s2 += y * y; }
#pragma unroll
    for (int off = 1; off < 16; off <<= 1) { s += __shfl_xor(s, off, 64); s2 += __shfl_xor(s2, off, 64); }
    ps[reg] = s; ps2[reg] = s2;
  }
  if (cl == 0) {
#pragma unroll
    for (int reg = 0; reg < 4; ++reg) {
      const int row = mg * 16 + q * 4 + reg;
      redS[ng][row] = ps[reg]; redS2[ng][row] = ps2[reg];
    }
  }
  __syncthreads();
  if (tid < 64) {
    const float s  = redS[0][tid] + redS[1][tid] + redS[2][tid] + redS[3][tid];
    const float s2 = redS2[0][tid] + redS2[1][tid] + redS2[2][tid] + redS2[3][tid];
    const float mu = s * (1.f / DD);
    const float var = s2 * (1.f / DD) - mu * mu;
    muL[tid] = mu; invL[tid] = rsqrtf(var + EPSLN);
  }
  __syncthreads();

#pragma unroll
  for (int nt = 0; nt < 4; ++nt) {
    const int col = ng * 64 + nt * 16 + cl;
    const float gv = g1[col], bv = b1[col];
#pragma unroll
    for (int reg = 0; reg < 4; ++reg) {
      const int row = mg * 16 + q * 4 + reg;
      const float hv = (acc[nt][reg] - muL[row]) * invL[row] * gv + bv;
      h[(tok0 + row) * DD + col] = f2bf(hv);
    }
  }
}

// ------------- kernel 2: FF1 + gelu + FF2 (chunked over H) + residual + LN2 ----
// 1024 threads = 16 waves = 4 m-groups x 4 n-groups.
__global__ __launch_bounds__(1024) void k_ffn_ln2(
    const u16* __restrict__ h, const u16* __restrict__ w1t,
    const float* __restrict__ bf1, const u16* __restrict__ w2t,
    const float* __restrict__ bf2, const float* __restrict__ g2,
    const float* __restrict__ b2, float* __restrict__ out)
{
  __shared__ u16 hs[64 * XPITCH];                    // 33.8 KB
  __shared__ u16 asb[64 * APITCH];                   // 17.4 KB
  __shared__ float redS[4][64], redS2[4][64];
  __shared__ float muL[64], invL[64];

  const int tid = threadIdx.x;
  const int wv = tid >> 6, l = tid & 63, q = l >> 4, cl = l & 15;
  const int mg = wv >> 2, ng = wv & 3;
  const long tok0 = (long)blockIdx.x * MT;

  // ---- stage h tile ----
  {
    const int chunk = tid & 31;
#pragma unroll
    for (int i = 0; i < 2; ++i) {
      const int row = (tid >> 5) + i * 32;
      const uint4 v = *(const uint4*)&h[(tok0 + row) * DD + chunk * 8];
      *(uint4*)&hs[row * XPITCH + chunk * 8] = v;
    }
  }
  __syncthreads();

  const int arow = mg * 16 + cl;

  // ---- FF2 accumulators (persist across chunks) ----
  f32x4 acc2[4];
#pragma unroll
  for (int nt = 0; nt < 4; ++nt) {
    const float bv = bf2[ng * 64 + nt * 16 + cl];
    acc2[nt] = (f32x4){bv, bv, bv, bv};
  }

  for (int c = 0; c < 8; ++c) {                      // 8 chunks of 128 H-cols
    // ---- FF1: this wave's 16 rows x 32 cols of the chunk ----
    f32x4 acc1[2];
#pragma unroll
    for (int nt = 0; nt < 2; ++nt) {
      const float bv = bf1[c * 128 + ng * 32 + nt * 16 + cl];
      acc1[nt] = (f32x4){bv, bv, bv, bv};
    }
#pragma unroll
    for (int s = 0; s < 8; ++s) {                    // K = 256
      const short8 a = *(const short8*)&hs[arow * XPITCH + s * 32 + q * 8];
#pragma unroll
      for (int nt = 0; nt < 2; ++nt) {
        const short8 b = *(const short8*)&w1t[(size_t)(c * 128 + ng * 32 + nt * 16 + cl) * DD + s * 32 + q * 8];
        acc1[nt] = MFMA(a, b, acc1[nt]);
      }
    }
    // ---- exact gelu, scatter bf16 into asb (A-layout for FF2) ----
#pragma unroll
    for (int nt = 0; nt < 2; ++nt)
#pragma unroll
      for (int reg = 0; reg < 4; ++reg) {
        const float v = acc1[nt][reg];
        const float g = 0.5f * v * (1.f + erff(v * 0.70710678118654752f));
        asb[(mg * 16 + q * 4 + reg) * APITCH + ng * 32 + nt * 16 + cl] = f2bf(g);
      }
    __syncthreads();
    // ---- FF2 partial over this chunk's 128 K ----
#pragma unroll
    for (int s = 0; s < 4; ++s) {
      const short8 a = *(const short8*)&asb[arow * APITCH + s * 32 + q * 8];
#pragma unroll
      for (int nt = 0; nt < 4; ++nt) {
        const short8 b = *(const short8*)&w2t[(size_t)(ng * 64 + nt * 16 + cl) * HH + c * 128 + s * 32 + q * 8];
        acc2[nt] = MFMA(a, b, acc2[nt]);
      }
    }
    __syncthreads();                                 // asb reusable next chunk
  }

  // ---- residual (h bf16 from LDS) ----
#pragma unroll
  for (int nt = 0; nt < 4; ++nt) {
    const int col = ng * 64 + nt * 16 + cl;
#pragma unroll
    for (int reg = 0; reg < 4; ++reg) {
      const int row = mg * 16 + q * 4 + reg;
      acc2[nt][reg] += bf2f(hs[row * XPITCH + col]);
    }
  }

  // ---- LN2 ----
  float ps[4], ps2[4];
#pragma unroll
  for (int reg = 0; reg < 4; ++reg) {
    float s = 0.f, s2 = 0.f;
#pragma unroll
    for (int nt = 0; nt < 4; ++nt) { const float y = acc2[nt][reg]; s += y; s2 += y * y; }
#pragma unroll
    for (int off = 1; off < 16; off <<= 1) { s += __shfl_xor(s, off, 64); s2 += __shfl_xor(s2, off, 64); }
    ps[reg] = s; ps2[reg] = s2;
  }
  if (cl == 0) {
#pragma unroll
    for (int reg = 0; reg < 4; ++reg) {
      const int row = mg * 16 + q * 4 + reg;
      redS[ng][row] = ps[reg]; redS2[ng][row] = ps2[reg];
    }
  }
  __syncthreads();
  if (tid < 64) {
    const float s  = redS[0][tid] + redS[1][tid] + redS[2][tid] + redS[3][tid];
    const float s2 = redS2[0][tid] + redS2[1][tid] + redS2[2][tid] + redS2[3][tid];
    const float mu = s * (1.f / DD);
    const float var = s2 * (1.f / DD) - mu * mu;
    muL[tid] = mu; invL[tid] = rsqrtf(var + EPSLN);
  }
  __syncthreads();

#pragma unroll
  for (int nt = 0; nt < 4; ++nt) {
    const int col = ng * 64 + nt * 16 + cl;
    const float gv = g2[col], bv = b2[col];
#pragma unroll
    for (int reg = 0; reg < 4; ++reg) {
      const int row = mg * 16 + q * 4 + reg;
      out[(tok0 + row) * DD + col] = (acc2[nt][reg] - muL[row]) * invL[row] * gv + bv;
    }
  }
}

// ---------------- launch ----------------
extern "C" void kernel_launch(void* const* d_in, const int* in_sizes, int n_in,
                              void* d_out, int out_size, void* d_ws, size_t ws_size,
                              hipStream_t stream) {
  const float* x    = (const float*)d_in[0];
  const float* wmix = (const float*)d_in[1];   // [3840][256]
  const float* bmix = (const float*)d_in[2];
  const float* g1   = (const float*)d_in[3];
  const float* b1   = (const float*)d_in[4];
  const float* wff1 = (const float*)d_in[5];   // [256][1024]
  const float* bff1 = (const float*)d_in[6];
  const float* wff2 = (const float*)d_in[7];   // [1024][256]
  const float* bff2 = (const float*)d_in[8];
  const float* g2   = (const float*)d_in[9];
  const float* b2   = (const float*)d_in[10];
  float* out = (float*)d_out;

  u16* wmt = (u16*)d_ws;                 // [256][3840] bf16  (1.97 MB)
  u16* w1t = wmt + 983040;               // [1024][256] bf16  (0.5 MB)
  u16* w2t = w1t + 262144;               // [256][1024] bf16  (0.5 MB)
  u16* hb  = w2t + 262144;               // [16384][256] bf16 (8 MB)

  k_prep<<<1472, 256, 0, stream>>>(wmix, wff1, wff2, wmt, w1t, w2t);

  const int R = 4 * NNSEQ;               // 16384 tokens
  k_mix_ln1 <<<R / MT, 1024, 0, stream>>>(x, wmt, bmix, g1, b1, hb);
  k_ffn_ln2 <<<R / MT, 1024, 0, stream>>>(hb, w1t, bff1, w2t, bff2, g2, b2, out);
}

// Round 4
// 173.994 us; speedup vs baseline: 2.4527x; 2.4527x over previous
//
#include <hip/hip_runtime.h>
#include <cstdint>

// ---------------- problem constants ----------------
#define DD     256
#define HH     1024
#define NNSEQ  4096
#define KDIM   3840          // 15 * 256 (conv-as-GEMM K)
#define NSTEPS 120           // KDIM / 32
#define MT     64            // tokens per block (both GEMM kernels)
#define XROWS  78            // MT + 14 halo rows
#define XPITCH 264           // 256 + 8 pad (bf16 elems)
#define APITCH 136           // 128 + 8 pad
#define EPSLN  1e-5f

typedef unsigned short u16;
typedef __attribute__((ext_vector_type(8))) short short8;
typedef __attribute__((ext_vector_type(4))) float f32x4;

#define MFMA(a, b, c) __builtin_amdgcn_mfma_f32_16x16x32_bf16(a, b, c, 0, 0, 0)

__device__ __forceinline__ u16 f2bf(float f) {           // RNE fp32 -> bf16
  unsigned u = __float_as_uint(f);
  u += 0x7FFF + ((u >> 16) & 1);
  return (u16)(u >> 16);
}
__device__ __forceinline__ float bf2f(u16 s) { return __uint_as_float(((unsigned)s) << 16); }

// ======== prep: pack all weights into MFMA B-fragment order (bf16) ========
// wpk : [s(120)][ng(4)][nt(4)][lane(64)][8]   frag value = wmix[(s*32+q*8+j)*256 + ng*64+nt*16+cl]
// w1pk: [c(8)][s(8)][ng(4)][nt(2)][lane][8]   = wff1[(s*32+q*8+j)*1024 + c*128+ng*32+nt*16+cl]
// w2pk: [c(8)][s(4)][ng(4)][nt(4)][lane][8]   = wff2[(c*128+s*32+q*8+j)*256 + ng*64+nt*16+cl]
__global__ __launch_bounds__(256) void k_prep(
    const float* __restrict__ wmix, const float* __restrict__ wff1,
    const float* __restrict__ wff2, u16* __restrict__ wpk,
    u16* __restrict__ w1pk, u16* __restrict__ w2pk)
{
  __shared__ float t[32][257];
  const int b = blockIdx.x, tid = threadIdx.x;

  if (b < 120) {                                   // ---- conv weights ----
    const int s = b;
    for (int r = 0; r < 32; ++r)
      t[r][tid] = wmix[(size_t)(s * 32 + r) * 256 + tid];
    __syncthreads();
#pragma unroll
    for (int f = 0; f < 4; ++f) {                  // frag F = f*256 + tid
      const int l = tid & 63, q = l >> 4, cl = l & 15;
      const int nt = (tid >> 6) & 3, ng = f;
      const int n = ng * 64 + nt * 16 + cl;
      uint4 pk;
      unsigned* p = (unsigned*)&pk;
#pragma unroll
      for (int jj = 0; jj < 4; ++jj)
        p[jj] = (unsigned)f2bf(t[q * 8 + jj * 2][n]) | ((unsigned)f2bf(t[q * 8 + jj * 2 + 1][n]) << 16);
      *(uint4*)&wpk[((size_t)s * 1024 + f * 256 + tid) * 8] = pk;
    }
  } else if (b < 184) {                            // ---- FF1 weights ----
    const int u = b - 120, c = u >> 3, s = u & 7;
    for (int i = 0; i < 16; ++i) {
      const int r = i * 2 + (tid >> 7), col = tid & 127;
      t[r][col] = wff1[(size_t)(s * 32 + r) * 1024 + c * 128 + col];
    }
    __syncthreads();
#pragma unroll
    for (int f = 0; f < 2; ++f) {
      const int l = tid & 63, q = l >> 4, cl = l & 15;
      const int nt = (tid >> 6) & 1, ng = f * 2 + (tid >> 7);
      const int n = ng * 32 + nt * 16 + cl;
      uint4 pk;
      unsigned* p = (unsigned*)&pk;
#pragma unroll
      for (int jj = 0; jj < 4; ++jj)
        p[jj] = (unsigned)f2bf(t[q * 8 + jj * 2][n]) | ((unsigned)f2bf(t[q * 8 + jj * 2 + 1][n]) << 16);
      *(uint4*)&w1pk[((size_t)(c * 8 + s) * 512 + f * 256 + tid) * 8] = pk;
    }
  } else {                                         // ---- FF2 weights ----
    const int u = b - 184, c = u >> 2, s = u & 3;
    for (int r = 0; r < 32; ++r)
      t[r][tid] = wff2[(size_t)(c * 128 + s * 32 + r) * 256 + tid];
    __syncthreads();
#pragma unroll
    for (int f = 0; f < 4; ++f) {
      const int l = tid & 63, q = l >> 4, cl = l & 15;
      const int nt = (tid >> 6) & 3, ng = f;
      const int n = ng * 64 + nt * 16 + cl;
      uint4 pk;
      unsigned* p = (unsigned*)&pk;
#pragma unroll
      for (int jj = 0; jj < 4; ++jj)
        p[jj] = (unsigned)f2bf(t[q * 8 + jj * 2][n]) | ((unsigned)f2bf(t[q * 8 + jj * 2 + 1][n]) << 16);
      *(uint4*)&w2pk[((size_t)(c * 4 + s) * 1024 + f * 256 + tid) * 8] = pk;
    }
  }
}

// ===== kernel 1: causal conv (MFMA) + residual + LN1 -> h (bf16) =====
// 512 thr = 8 waves = 2 m-groups x 4 n-groups; wave tile 32m x 64n.
__global__ __launch_bounds__(512) void k_mix_ln1(
    const float* __restrict__ x, const u16* __restrict__ wpk,
    const float* __restrict__ bmix, const float* __restrict__ g1,
    const float* __restrict__ b1, u16* __restrict__ h)
{
  __shared__ u16 xs[XROWS * XPITCH];               // 41.2 KB
  __shared__ float redS[4][64], redS2[4][64];
  __shared__ float muL[64], invL[64];

  const int tid = threadIdx.x;
  const int wv = tid >> 6, l = tid & 63, q = l >> 4, cl = l & 15;
  const int mg = wv >> 2, ng = wv & 3;
  const long tok0 = (long)blockIdx.x * MT;
  const int n0 = (int)(tok0 & (NNSEQ - 1));

  // ---- stage x rows [tok0-14, tok0+63] as bf16 into LDS ----
  {
    const int cslot = (tid & 63) * 4;
    for (int r = tid >> 6; r < XROWS; r += 8) {
      const int nloc = n0 - 14 + r;
      float4 v = make_float4(0.f, 0.f, 0.f, 0.f);
      if (nloc >= 0) v = *(const float4*)&x[(tok0 - 14 + r) * DD + cslot];
      uint2 pk;
      pk.x = (unsigned)f2bf(v.x) | ((unsigned)f2bf(v.y) << 16);
      pk.y = (unsigned)f2bf(v.z) | ((unsigned)f2bf(v.w) << 16);
      *(uint2*)&xs[r * XPITCH + cslot] = pk;
    }
  }
  __syncthreads();

  f32x4 acc[2][4];
#pragma unroll
  for (int nt = 0; nt < 4; ++nt) {
    const float bm = bmix[ng * 64 + nt * 16 + cl];
#pragma unroll
    for (int mt = 0; mt < 2; ++mt) acc[mt][nt] = (f32x4){bm, bm, bm, bm};
  }

  const u16* bbase = wpk + (size_t)(ng * 4) * 512 + (size_t)l * 8;   // + s*(4*4*512) + nt*512

#define LOAD_A(dst, s_)                                                        \
  {                                                                            \
    const int xrow = (s_) >> 3, c0 = ((s_) & 7) * 32;                          \
    _Pragma("unroll")                                                          \
    for (int mt = 0; mt < 2; ++mt)                                             \
      dst[mt] = *(const short8*)&xs[(xrow + mg * 32 + mt * 16 + cl) * XPITCH + c0 + q * 8]; \
  }
#define LOAD_B(dst, s_)                                                        \
  {                                                                            \
    const u16* bp = bbase + (size_t)(s_) * 8192;                               \
    _Pragma("unroll")                                                          \
    for (int nt = 0; nt < 4; ++nt)                                             \
      dst[nt] = *(const short8*)(bp + nt * 512);                               \
  }

  short8 af[3][2], bfr[3][4];
  LOAD_A(af[0], 0) LOAD_B(bfr[0], 0)
  LOAD_A(af[1], 1) LOAD_B(bfr[1], 1)
  LOAD_A(af[2], 2) LOAD_B(bfr[2], 2)

#pragma unroll 3
  for (int s = 0; s < NSTEPS; ++s) {
    const int cur = s % 3;
#pragma unroll
    for (int mt = 0; mt < 2; ++mt)
#pragma unroll
      for (int nt = 0; nt < 4; ++nt)
        acc[mt][nt] = MFMA(af[cur][mt], bfr[cur][nt], acc[mt][nt]);
    if (s + 3 < NSTEPS) {
      LOAD_A(af[cur], s + 3)
      LOAD_B(bfr[cur], s + 3)
    }
  }

  // ---- residual (fp32 x) ----
#pragma unroll
  for (int mt = 0; mt < 2; ++mt)
#pragma unroll
    for (int nt = 0; nt < 4; ++nt) {
      const int col = ng * 64 + nt * 16 + cl;
#pragma unroll
      for (int reg = 0; reg < 4; ++reg) {
        const int row = mg * 32 + mt * 16 + q * 4 + reg;
        acc[mt][nt][reg] += x[(tok0 + row) * DD + col];
      }
    }

  // ---- LN1 ----
  float ps[2][4], ps2[2][4];
#pragma unroll
  for (int mt = 0; mt < 2; ++mt)
#pragma unroll
    for (int reg = 0; reg < 4; ++reg) {
      float s = 0.f, s2 = 0.f;
#pragma unroll
      for (int nt = 0; nt < 4; ++nt) { const float y = acc[mt][nt][reg]; s += y; s2 += y * y; }
#pragma unroll
      for (int off = 1; off < 16; off <<= 1) { s += __shfl_xor(s, off, 64); s2 += __shfl_xor(s2, off, 64); }
      ps[mt][reg] = s; ps2[mt][reg] = s2;
    }
  if (cl == 0) {
#pragma unroll
    for (int mt = 0; mt < 2; ++mt)
#pragma unroll
      for (int reg = 0; reg < 4; ++reg) {
        const int row = mg * 32 + mt * 16 + q * 4 + reg;
        redS[ng][row] = ps[mt][reg]; redS2[ng][row] = ps2[mt][reg];
      }
  }
  __syncthreads();
  if (tid < 64) {
    const float s  = redS[0][tid] + redS[1][tid] + redS[2][tid] + redS[3][tid];
    const float s2 = redS2[0][tid] + redS2[1][tid] + redS2[2][tid] + redS2[3][tid];
    const float mu = s * (1.f / DD);
    const float var = s2 * (1.f / DD) - mu * mu;
    muL[tid] = mu; invL[tid] = rsqrtf(var + EPSLN);
  }
  __syncthreads();

#pragma unroll
  for (int nt = 0; nt < 4; ++nt) {
    const int col = ng * 64 + nt * 16 + cl;
    const float gv = g1[col], bv = b1[col];
#pragma unroll
    for (int mt = 0; mt < 2; ++mt)
#pragma unroll
      for (int reg = 0; reg < 4; ++reg) {
        const int row = mg * 32 + mt * 16 + q * 4 + reg;
        const float hv = (acc[mt][nt][reg] - muL[row]) * invL[row] * gv + bv;
        h[(tok0 + row) * DD + col] = f2bf(hv);
      }
  }
#undef LOAD_A
#undef LOAD_B
}

// ===== kernel 2: FF1 + gelu + FF2 (chunked over H) + residual + LN2 =====
// 512 thr = 8 waves = 2 m-groups x 4 n-groups.
__global__ __launch_bounds__(512) void k_ffn_ln2(
    const u16* __restrict__ h, const u16* __restrict__ w1pk,
    const float* __restrict__ bf1, const u16* __restrict__ w2pk,
    const float* __restrict__ bf2, const float* __restrict__ g2,
    const float* __restrict__ b2, float* __restrict__ out)
{
  __shared__ u16 hs[64 * XPITCH];                  // 33.8 KB
  __shared__ u16 asb[64 * APITCH];                 // 17.4 KB
  __shared__ float redS[4][64], redS2[4][64];
  __shared__ float muL[64], invL[64];

  const int tid = threadIdx.x;
  const int wv = tid >> 6, l = tid & 63, q = l >> 4, cl = l & 15;
  const int mg = wv >> 2, ng = wv & 3;
  const long tok0 = (long)blockIdx.x * MT;

  // ---- stage h tile ----
  {
    const int chunk = tid & 31;
#pragma unroll
    for (int i = 0; i < 4; ++i) {
      const int row = (tid >> 5) + i * 16;
      const uint4 v = *(const uint4*)&h[(tok0 + row) * DD + chunk * 8];
      *(uint4*)&hs[row * XPITCH + chunk * 8] = v;
    }
  }
  __syncthreads();

  f32x4 acc2[2][4];
#pragma unroll
  for (int nt = 0; nt < 4; ++nt) {
    const float bv = bf2[ng * 64 + nt * 16 + cl];
#pragma unroll
    for (int mt = 0; mt < 2; ++mt) acc2[mt][nt] = (f32x4){bv, bv, bv, bv};
  }

  for (int c = 0; c < 8; ++c) {                    // 8 chunks of 128 H-cols
    // ---- FF1: wave tile 32m x 32n of this chunk ----
    f32x4 acc1[2][2];
#pragma unroll
    for (int nt = 0; nt < 2; ++nt) {
      const float bv = bf1[c * 128 + ng * 32 + nt * 16 + cl];
#pragma unroll
      for (int mt = 0; mt < 2; ++mt) acc1[mt][nt] = (f32x4){bv, bv, bv, bv};
    }
#pragma unroll
    for (int s = 0; s < 8; ++s) {                  // K = 256
      short8 a[2], b[2];
#pragma unroll
      for (int mt = 0; mt < 2; ++mt)
        a[mt] = *(const short8*)&hs[(mg * 32 + mt * 16 + cl) * XPITCH + s * 32 + q * 8];
      const u16* bp = w1pk + ((size_t)((c * 8 + s) * 4 + ng) * 2) * 512 + (size_t)l * 8;
#pragma unroll
      for (int nt = 0; nt < 2; ++nt)
        b[nt] = *(const short8*)(bp + nt * 512);
#pragma unroll
      for (int mt = 0; mt < 2; ++mt)
#pragma unroll
        for (int nt = 0; nt < 2; ++nt)
          acc1[mt][nt] = MFMA(a[mt], b[nt], acc1[mt][nt]);
    }
    // ---- exact gelu -> asb (A-layout for FF2) ----
#pragma unroll
    for (int mt = 0; mt < 2; ++mt)
#pragma unroll
      for (int nt = 0; nt < 2; ++nt)
#pragma unroll
        for (int reg = 0; reg < 4; ++reg) {
          const float v = acc1[mt][nt][reg];
          const float g = 0.5f * v * (1.f + erff(v * 0.70710678118654752f));
          asb[(mg * 32 + mt * 16 + q * 4 + reg) * APITCH + ng * 32 + nt * 16 + cl] = f2bf(g);
        }
    __syncthreads();
    // ---- FF2 partial over this chunk's 128 K ----
#pragma unroll
    for (int s = 0; s < 4; ++s) {
      short8 a[2], b[4];
#pragma unroll
      for (int mt = 0; mt < 2; ++mt)
        a[mt] = *(const short8*)&asb[(mg * 32 + mt * 16 + cl) * APITCH + s * 32 + q * 8];
      const u16* bp = w2pk + ((size_t)((c * 4 + s) * 4 + ng) * 4) * 512 + (size_t)l * 8;
#pragma unroll
      for (int nt = 0; nt < 4; ++nt)
        b[nt] = *(const short8*)(bp + nt * 512);
#pragma unroll
      for (int mt = 0; mt < 2; ++mt)
#pragma unroll
        for (int nt = 0; nt < 4; ++nt)
          acc2[mt][nt] = MFMA(a[mt], b[nt], acc2[mt][nt]);
    }
    __syncthreads();
  }

  // ---- residual (h bf16 from LDS) ----
#pragma unroll
  for (int mt = 0; mt < 2; ++mt)
#pragma unroll
    for (int nt = 0; nt < 4; ++nt) {
      const int col = ng * 64 + nt * 16 + cl;
#pragma unroll
      for (int reg = 0; reg < 4; ++reg) {
        const int row = mg * 32 + mt * 16 + q * 4 + reg;
        acc2[mt][nt][reg] += bf2f(hs[row * XPITCH + col]);
      }
    }

  // ---- LN2 ----
  float ps[2][4], ps2[2][4];
#pragma unroll
  for (int mt = 0; mt < 2; ++mt)
#pragma unroll
    for (int reg = 0; reg < 4; ++reg) {
      float s = 0.f, s2 = 0.f;
#pragma unroll
      for (int nt = 0; nt < 4; ++nt) { const float y = acc2[mt][nt][reg]; s += y; s2 += y * y; }
#pragma unroll
      for (int off = 1; off < 16; off <<= 1) { s += __shfl_xor(s, off, 64); s2 += __shfl_xor(s2, off, 64); }
      ps[mt][reg] = s; ps2[mt][reg] = s2;
    }
  if (cl == 0) {
#pragma unroll
    for (int mt = 0; mt < 2; ++mt)
#pragma unroll
      for (int reg = 0; reg < 4; ++reg) {
        const int row = mg * 32 + mt * 16 + q * 4 + reg;
        redS[ng][row] = ps[mt][reg]; redS2[ng][row] = ps2[mt][reg];
      }
  }
  __syncthreads();
  if (tid < 64) {
    const float s  = redS[0][tid] + redS[1][tid] + redS[2][tid] + redS[3][tid];
    const float s2 = redS2[0][tid] + redS2[1][tid] + redS2[2][tid] + redS2[3][tid];
    const float mu = s * (1.f / DD);
    const float var = s2 * (1.f / DD) - mu * mu;
    muL[tid] = mu; invL[tid] = rsqrtf(var + EPSLN);
  }
  __syncthreads();

#pragma unroll
  for (int nt = 0; nt < 4; ++nt) {
    const int col = ng * 64 + nt * 16 + cl;
    const float gv = g2[col], bv = b2[col];
#pragma unroll
    for (int mt = 0; mt < 2; ++mt)
#pragma unroll
      for (int reg = 0; reg < 4; ++reg) {
        const int row = mg * 32 + mt * 16 + q * 4 + reg;
        out[(tok0 + row) * DD + col] = (acc2[mt][nt][reg] - muL[row]) * invL[row] * gv + bv;
      }
  }
}

// ---------------- launch ----------------
extern "C" void kernel_launch(void* const* d_in, const int* in_sizes, int n_in,
                              void* d_out, int out_size, void* d_ws, size_t ws_size,
                              hipStream_t stream) {
  const float* x    = (const float*)d_in[0];
  const float* wmix = (const float*)d_in[1];   // [3840][256]
  const float* bmix = (const float*)d_in[2];
  const float* g1   = (const float*)d_in[3];
  const float* b1   = (const float*)d_in[4];
  const float* wff1 = (const float*)d_in[5];   // [256][1024]
  const float* bff1 = (const float*)d_in[6];
  const float* wff2 = (const float*)d_in[7];   // [1024][256]
  const float* bff2 = (const float*)d_in[8];
  const float* g2   = (const float*)d_in[9];
  const float* b2   = (const float*)d_in[10];
  float* out = (float*)d_out;

  u16* wpk  = (u16*)d_ws;                // 983040 elems (1.97 MB)
  u16* w1pk = wpk + 983040;              // 262144
  u16* w2pk = w1pk + 262144;             // 262144
  u16* hb   = w2pk + 262144;             // 16384*256 bf16 (8 MB)

  k_prep<<<216, 256, 0, stream>>>(wmix, wff1, wff2, wpk, w1pk, w2pk);

  const int R = 4 * NNSEQ;               // 16384 tokens
  k_mix_ln1 <<<R / MT, 512, 0, stream>>>(x, wpk, bmix, g1, b1, hb);
  k_ffn_ln2 <<<R / MT, 512, 0, stream>>>(hb, w1pk, bff1, w2pk, bff2, g2, b2, out);
}